// Round 1
// baseline (595.112 us; speedup 1.0000x reference)
//
#include <hip/hip_runtime.h>

// Problem constants
#define N_NODES 49152
#define FDIM    128
#define DDIM    9
#define NB      16                       // nodes per block
#define NBLK    (N_NODES / NB)           // 3072
#define OUT2_OFF ((size_t)N_NODES * FDIM * DDIM)

// ws layout (ushort elements): Wq[3][128][128], Wk, Wv, ls_w[256][128], lvs_w[128][128]
#define WQ_OFF   0
#define WK_OFF   49152
#define WV_OFF   98304
#define LS_OFF   147456
#define LVS_OFF  180224
#define WS_ELEMS 196608

typedef __bf16 bf16x8 __attribute__((ext_vector_type(8)));
typedef float  floatx4 __attribute__((ext_vector_type(4)));
typedef unsigned short ushortx4 __attribute__((ext_vector_type(4)));

__device__ __forceinline__ unsigned short f2bf(float f) {
    unsigned u = __float_as_uint(f);
    u += 0x7FFFu + ((u >> 16) & 1u);      // RNE; inputs are finite Gaussians
    return (unsigned short)(u >> 16);
}

__device__ __forceinline__ floatx4 mfma16(bf16x8 a, bf16x8 b, floatx4 c) {
    return __builtin_amdgcn_mfma_f32_16x16x32_bf16(a, b, c, 0, 0, 0);
}

// ---------------- prep: cast all weights to bf16 into ws ----------------
__global__ void prep_kernel(const float* __restrict__ Wq, const float* __restrict__ Wk,
                            const float* __restrict__ Wv, const float* __restrict__ lsw,
                            const float* __restrict__ lvw, unsigned short* __restrict__ ws) {
    int i = blockIdx.x * 256 + threadIdx.x;
    if (i >= WS_ELEMS) return;
    float v;
    if      (i < WK_OFF)  v = Wq[i - WQ_OFF];
    else if (i < WV_OFF)  v = Wk[i - WK_OFF];
    else if (i < LS_OFF)  v = Wv[i - WV_OFF];
    else if (i < LVS_OFF) v = lsw[i - LS_OFF];
    else                  v = lvw[i - LVS_OFF];
    ws[i] = f2bf(v);
}

// ---------------- fused main kernel ----------------
// LDS 49920 B -> 3 blocks/CU (was 67584 -> 2 blocks/CU).
// p (softmax probs) now lives entirely in registers via the logit tile remap:
//   wave w computes row tiles {2w, 2w+1, 8+2w, 9+2w}; each lane's lg[rt][r]
//   is exactly the su (rt<2) / sd (rt>=2) value it consumes in phases 5/6.
struct SMem {
    unsigned short ttr[NB * DDIM * 136];  // T transposed [n][dd][u], bf16, pad 136 (39168 B)
    unsigned short sS[NB * 136];          // S bf16 [n][u]
    unsigned short sbuf[NB * 136];        // s bf16 [n][u]
    float w2l[3 * FDIM];                  // w2 fp32
    float redA[64];
    float redB[64];
};

__global__ void __launch_bounds__(256, 3)
tpattn_main(const float* __restrict__ T, const float* __restrict__ S,
            const float* __restrict__ w2, const float* __restrict__ ls_b,
            const float* __restrict__ lvs_b, const unsigned short* __restrict__ wbf,
            float* __restrict__ out) {
    __shared__ SMem sm;
    const int tid  = threadIdx.x;
    const int w    = tid >> 6;       // wave 0..3
    const int lane = tid & 63;
    const int quad = lane >> 4;
    const int m16  = lane & 15;      // node col for B/D; row for A loads
    const int n0   = blockIdx.x * NB;

    const unsigned short* Wq  = wbf + WQ_OFF;
    const unsigned short* Wk  = wbf + WK_OFF;
    const unsigned short* Wv  = wbf + WV_OFF;
    const unsigned short* Lsw = wbf + LS_OFF;
    const unsigned short* Lvw = wbf + LVS_OFF;

    constexpr int   DL[3]  = {1, 3, 5};
    constexpr int   OL[3]  = {0, 1, 4};
    constexpr float C1A[3] = {0.57735026919f, 0.33333333333f, 0.25819888975f};
    const float INV_F  = 0.0078125f;           // 1/128 (q*k scaling)
    const float INV_SF = 0.08838834764831845f; // 1/sqrt(128)

    // ---- phase 0: stage T (bf16, transposed), S (bf16), w2 ----
    {
        const float4* Tg = (const float4*)(T + (size_t)n0 * 1152);
        // incremental (t9, dd) tracking: le = t9*9 + dd; start le = tid*4,
        // advance by 1024 elements per it (1024 = 113*9 + 7).
        int t9 = (tid * 4) / 9;
        int dd = tid * 4 - t9 * 9;
        #pragma unroll
        for (int it = 0; it < 18; ++it) {
            float4 val = Tg[it * 256 + tid];
            float vv[4] = {val.x, val.y, val.z, val.w};
            int t9c = t9, ddc = dd;
            #pragma unroll
            for (int e = 0; e < 4; ++e) {
                int n  = t9c >> 7;
                int uu = t9c & 127;
                sm.ttr[(n * 9 + ddc) * 136 + uu] = f2bf(vv[e]);
                ++ddc; if (ddc == 9) { ddc = 0; ++t9c; }
            }
            t9 += 113; dd += 7; if (dd >= 9) { dd -= 9; ++t9; }
        }
        const float4* Sg = (const float4*)(S + (size_t)n0 * 128);
        #pragma unroll
        for (int it = 0; it < 2; ++it) {
            int lin = (it * 256 + tid) * 4;
            float4 val = Sg[it * 256 + tid];
            int n = lin >> 7, uu = lin & 127;
            ushortx4 pk = { f2bf(val.x), f2bf(val.y), f2bf(val.z), f2bf(val.w) };
            *(ushortx4*)(&sm.sS[n * 136 + uu]) = pk;
        }
        for (int i = tid; i < 3 * FDIM; i += 256) sm.w2l[i] = w2[i];
    }
    __syncthreads();

    // ---- phase 2: q,k projections + in-lane s = sum_d C1 q k ----
    float sf[2][4] = {{0.f,0.f,0.f,0.f},{0.f,0.f,0.f,0.f}};
    #pragma unroll
    for (int l = 0; l < 3; ++l) {
        bf16x8 aq[2][4], ak[2][4];
        #pragma unroll
        for (int vt = 0; vt < 2; ++vt)
            #pragma unroll
            for (int kc = 0; kc < 4; ++kc) {
                int v  = w * 32 + vt * 16 + m16;
                int u0 = kc * 32 + quad * 8;
                aq[vt][kc] = *(const bf16x8*)(Wq + (l * 128 + v) * 128 + u0);
                ak[vt][kc] = *(const bf16x8*)(Wk + (l * 128 + v) * 128 + u0);
            }
        #pragma unroll
        for (int j = 0; j < DL[l]; ++j) {
            int jj = OL[l] + j;
            bf16x8 b[4];
            #pragma unroll
            for (int kc = 0; kc < 4; ++kc)
                b[kc] = *(const bf16x8*)(&sm.ttr[(m16 * 9 + jj) * 136 + kc * 32 + quad * 8]);
            floatx4 q0 = {0.f,0.f,0.f,0.f}, q1 = {0.f,0.f,0.f,0.f};
            floatx4 k0 = {0.f,0.f,0.f,0.f}, k1 = {0.f,0.f,0.f,0.f};
            #pragma unroll
            for (int kc = 0; kc < 4; ++kc) {
                q0 = mfma16(aq[0][kc], b[kc], q0);
                q1 = mfma16(aq[1][kc], b[kc], q1);
                k0 = mfma16(ak[0][kc], b[kc], k0);
                k1 = mfma16(ak[1][kc], b[kc], k1);
            }
            #pragma unroll
            for (int r = 0; r < 4; ++r) {
                sf[0][r] += C1A[l] * q0[r] * k0[r];
                sf[1][r] += C1A[l] * q1[r] * k1[r];
            }
        }
    }
    #pragma unroll
    for (int vt = 0; vt < 2; ++vt)
        #pragma unroll
        for (int r = 0; r < 4; ++r) {
            int uu = w * 32 + vt * 16 + quad * 4 + r;
            sm.sbuf[m16 * 136 + uu] = f2bf(sf[vt][r] * INV_F);
        }
    __syncthreads();

    // ---- phase 3: logits = ls_w @ s + ls_b ----
    // wave w owns row tiles {2w, 2w+1, 8+2w, 9+2w} so that lg[rt][r] is the
    // p value this very lane needs later (su: rt 0,1; sd: rt 2,3).
    float lg[4][4];
    {
        bf16x8 bs[4];
        #pragma unroll
        for (int kc = 0; kc < 4; ++kc)
            bs[kc] = *(const bf16x8*)(&sm.sbuf[m16 * 136 + kc * 32 + quad * 8]);
        #pragma unroll
        for (int rt = 0; rt < 4; ++rt) {
            int tile = (rt < 2) ? (2 * w + rt) : (6 + 2 * w + rt);  // 8+2w+(rt-2)
            floatx4 acc = {0.f,0.f,0.f,0.f};
            int ia = tile * 16 + m16;
            #pragma unroll
            for (int kc = 0; kc < 4; ++kc) {
                bf16x8 a = *(const bf16x8*)(Lsw + ia * 128 + kc * 32 + quad * 8);
                acc = mfma16(a, bs[kc], acc);
            }
            int i0 = tile * 16 + quad * 4;
            float4 bias = *(const float4*)(ls_b + i0);
            lg[rt][0] = acc[0] + bias.x;
            lg[rt][1] = acc[1] + bias.y;
            lg[rt][2] = acc[2] + bias.z;
            lg[rt][3] = acc[3] + bias.w;
        }
    }

    // ---- phase 4: softmax over 256 per node (col = m16); result stays in lg ----
    {
        float mx = lg[0][0];
        #pragma unroll
        for (int rt = 0; rt < 4; ++rt)
            #pragma unroll
            for (int r = 0; r < 4; ++r) mx = fmaxf(mx, lg[rt][r]);
        mx = fmaxf(mx, __shfl_xor(mx, 16, 64));
        mx = fmaxf(mx, __shfl_xor(mx, 32, 64));
        if (lane < 16) sm.redA[w * 16 + lane] = mx;
        __syncthreads();
        float m4 = fmaxf(fmaxf(sm.redA[m16], sm.redA[16 + m16]),
                         fmaxf(sm.redA[32 + m16], sm.redA[48 + m16]));
        float lsum = 0.f;
        #pragma unroll
        for (int rt = 0; rt < 4; ++rt)
            #pragma unroll
            for (int r = 0; r < 4; ++r) {
                float e = __expf(lg[rt][r] - m4);
                lg[rt][r] = e;
                lsum += e;
            }
        lsum += __shfl_xor(lsum, 16, 64);
        lsum += __shfl_xor(lsum, 32, 64);
        if (lane < 16) sm.redB[w * 16 + lane] = lsum;
        __syncthreads();
        float tot = sm.redB[m16] + sm.redB[16 + m16] + sm.redB[32 + m16] + sm.redB[48 + m16];
        float rinv = 1.0f / tot;
        #pragma unroll
        for (int rt = 0; rt < 4; ++rt)
            #pragma unroll
            for (int r = 0; r < 4; ++r)
                lg[rt][r] *= rinv;     // p values, kept in registers
    }
    // no barrier needed: phases 5/6 only read LDS written before phase 2's barrier

    // ---- phase 5: v projection + direct global stores (no LDS staging) ----
    float sdv[2][4];
    #pragma unroll
    for (int vt = 0; vt < 2; ++vt)
        #pragma unroll
        for (int r = 0; r < 4; ++r)
            sdv[vt][r] = lg[2 + vt][r] * INV_SF;   // sd * 1/sqrt(F) folded

    floatx4 vacc[9][2];
    #pragma unroll
    for (int l = 0; l < 3; ++l) {
        bf16x8 av[2][4];
        #pragma unroll
        for (int vt = 0; vt < 2; ++vt)
            #pragma unroll
            for (int kc = 0; kc < 4; ++kc) {
                int v  = w * 32 + vt * 16 + m16;
                int u0 = kc * 32 + quad * 8;
                av[vt][kc] = *(const bf16x8*)(Wv + (l * 128 + v) * 128 + u0);
            }
        #pragma unroll
        for (int j = 0; j < DL[l]; ++j) {
            int jj = OL[l] + j;
            bf16x8 b[4];
            #pragma unroll
            for (int kc = 0; kc < 4; ++kc)
                b[kc] = *(const bf16x8*)(&sm.ttr[(m16 * 9 + jj) * 136 + kc * 32 + quad * 8]);
            floatx4 a0 = {0.f,0.f,0.f,0.f}, a1 = {0.f,0.f,0.f,0.f};
            #pragma unroll
            for (int kc = 0; kc < 4; ++kc) {
                a0 = mfma16(av[0][kc], b[kc], a0);
                a1 = mfma16(av[1][kc], b[kc], a1);
            }
            vacc[jj][0] = a0;
            vacc[jj][1] = a1;
        }
    }

    // Each lane owns u0..u0+3 (all 9 dims) = 36 consecutive floats of node m16,
    // and u0 % 4 == 0 so the 36-float run is 16-B aligned: 9 aligned float4 stores.
    {
        float* outn = out + (size_t)(n0 + m16) * 1152;
        #pragma unroll
        for (int vt = 0; vt < 2; ++vt) {
            int u0 = w * 32 + vt * 16 + quad * 4;
            float vals[36];
            #pragma unroll
            for (int r = 0; r < 4; ++r) {
                int uu = u0 + r;
                float c0 = sdv[vt][r] * sm.w2l[uu];
                float c1 = sdv[vt][r] * sm.w2l[128 + uu];
                float c2 = sdv[vt][r] * sm.w2l[256 + uu];
                vals[r * 9 + 0] = vacc[0][vt][r] * c0;
                #pragma unroll
                for (int j = 0; j < 3; ++j) vals[r * 9 + 1 + j] = vacc[1 + j][vt][r] * c1;
                #pragma unroll
                for (int j = 0; j < 5; ++j) vals[r * 9 + 4 + j] = vacc[4 + j][vt][r] * c2;
            }
            float4* dst = (float4*)(outn + (size_t)u0 * 9);
            #pragma unroll
            for (int q4 = 0; q4 < 9; ++q4)
                dst[q4] = make_float4(vals[q4 * 4 + 0], vals[q4 * 4 + 1],
                                      vals[q4 * 4 + 2], vals[q4 * 4 + 3]);
        }
    }

    // ---- phase 6: out2 = su * silu(S @ lvs_w.T + lvs_b) ----
    {
        bf16x8 bS[4];
        #pragma unroll
        for (int kc = 0; kc < 4; ++kc)
            bS[kc] = *(const bf16x8*)(&sm.sS[m16 * 136 + kc * 32 + quad * 8]);
        #pragma unroll
        for (int rt = 0; rt < 2; ++rt) {
            floatx4 acc = {0.f,0.f,0.f,0.f};
            int ia = (2 * w + rt) * 16 + m16;
            #pragma unroll
            for (int kc = 0; kc < 4; ++kc) {
                bf16x8 a = *(const bf16x8*)(Lvw + ia * 128 + kc * 32 + quad * 8);
                acc = mfma16(a, bS[kc], acc);
            }
            int i0 = (2 * w + rt) * 16 + quad * 4;
            float4 bias = *(const float4*)(lvs_b + i0);
            float bb[4] = {bias.x, bias.y, bias.z, bias.w};
            float o4[4];
            #pragma unroll
            for (int r = 0; r < 4; ++r) {
                float z   = acc[r] + bb[r];
                float sig = 1.0f / (1.0f + __expf(-z));
                float su  = lg[rt][r];          // su from registers (tile 2w+rt)
                o4[r] = su * z * sig;
            }
            *(float4*)(out + OUT2_OFF + (size_t)(n0 + m16) * 128 + i0) =
                make_float4(o4[0], o4[1], o4[2], o4[3]);
        }
    }
}

extern "C" void kernel_launch(void* const* d_in, const int* in_sizes, int n_in,
                              void* d_out, int out_size, void* d_ws, size_t ws_size,
                              hipStream_t stream) {
    const float* T   = (const float*)d_in[0];
    const float* S   = (const float*)d_in[1];
    const float* Wq  = (const float*)d_in[2];
    const float* Wk  = (const float*)d_in[3];
    const float* Wv  = (const float*)d_in[4];
    const float* w2  = (const float*)d_in[5];
    const float* lsw = (const float*)d_in[6];
    const float* lsb = (const float*)d_in[7];
    const float* lvw = (const float*)d_in[8];
    const float* lvb = (const float*)d_in[9];
    float* out = (float*)d_out;
    unsigned short* wbf = (unsigned short*)d_ws;

    if (ws_size < WS_ELEMS * sizeof(unsigned short)) return;  // workspace guard (needs 384 KB)

    prep_kernel<<<(WS_ELEMS + 255) / 256, 256, 0, stream>>>(Wq, Wk, Wv, lsw, lvw, wbf);
    tpattn_main<<<NBLK, 256, 0, stream>>>(T, S, w2, lsb, lvb, wbf, out);
}

// Round 2
// 572.285 us; speedup vs baseline: 1.0399x; 1.0399x over previous
//
#include <hip/hip_runtime.h>

// Problem constants
#define N_NODES 49152
#define FDIM    128
#define DDIM    9
#define NB      16                       // nodes per block
#define NBLK    (N_NODES / NB)           // 3072
#define OUT2_OFF ((size_t)N_NODES * FDIM * DDIM)

// ws layout (ushort elements): Wq[3][128][128], Wk, Wv, ls_w[256][128], lvs_w[128][128]
#define WQ_OFF   0
#define WK_OFF   49152
#define WV_OFF   98304
#define LS_OFF   147456
#define LVS_OFF  180224
#define WS_ELEMS 196608

typedef __bf16 bf16x8 __attribute__((ext_vector_type(8)));
typedef float  floatx4 __attribute__((ext_vector_type(4)));
typedef unsigned short ushortx4 __attribute__((ext_vector_type(4)));

__device__ __forceinline__ unsigned short f2bf(float f) {
    unsigned u = __float_as_uint(f);
    u += 0x7FFFu + ((u >> 16) & 1u);      // RNE; inputs are finite Gaussians
    return (unsigned short)(u >> 16);
}

__device__ __forceinline__ floatx4 mfma16(bf16x8 a, bf16x8 b, floatx4 c) {
    return __builtin_amdgcn_mfma_f32_16x16x32_bf16(a, b, c, 0, 0, 0);
}

// ---------------- prep: cast all weights to bf16 into ws ----------------
__global__ void prep_kernel(const float* __restrict__ Wq, const float* __restrict__ Wk,
                            const float* __restrict__ Wv, const float* __restrict__ lsw,
                            const float* __restrict__ lvw, unsigned short* __restrict__ ws) {
    int i = blockIdx.x * 256 + threadIdx.x;
    if (i >= WS_ELEMS) return;
    float v;
    if      (i < WK_OFF)  v = Wq[i - WQ_OFF];
    else if (i < WV_OFF)  v = Wk[i - WK_OFF];
    else if (i < LS_OFF)  v = Wv[i - WV_OFF];
    else if (i < LVS_OFF) v = lsw[i - LS_OFF];
    else                  v = lvw[i - LVS_OFF];
    ws[i] = f2bf(v);
}

// ---------------- fused main kernel ----------------
// LDS 49920 B -> 3 blocks/CU. p (softmax probs) lives in registers via the
// logit tile remap (wave w owns tiles {2w, 2w+1, 8+2w, 9+2w}); tu goes out
// through LDS staging (union with ttr) so every HBM line is written fully
// by one wave instruction — round 1's direct 144-B-per-lane stores caused
// partial-line eviction (WRITE 245->388 MB, FETCH 132->200 MB).
struct SMem {
    union {
        unsigned short ttr[NB * DDIM * 136];  // T transposed [n][dd][u], bf16 (39168 B)
        float tu8[8 * 1160];                  // tu staging, 8 nodes, pad 1160 (37120 B)
    } u;
    unsigned short sS[NB * 136];              // S bf16 [n][u]
    unsigned short sbuf[NB * 136];            // s bf16 [n][u]
    float w2l[3 * FDIM];                      // w2 fp32
    float redA[64];
    float redB[64];
};

__global__ void __launch_bounds__(256, 3)
tpattn_main(const float* __restrict__ T, const float* __restrict__ S,
            const float* __restrict__ w2, const float* __restrict__ ls_b,
            const float* __restrict__ lvs_b, const unsigned short* __restrict__ wbf,
            float* __restrict__ out) {
    __shared__ SMem sm;
    const int tid  = threadIdx.x;
    const int w    = tid >> 6;       // wave 0..3
    const int lane = tid & 63;
    const int quad = lane >> 4;
    const int m16  = lane & 15;      // node col for B/D; row for A loads
    const int n0   = blockIdx.x * NB;

    const unsigned short* Wq  = wbf + WQ_OFF;
    const unsigned short* Wk  = wbf + WK_OFF;
    const unsigned short* Wv  = wbf + WV_OFF;
    const unsigned short* Lsw = wbf + LS_OFF;
    const unsigned short* Lvw = wbf + LVS_OFF;

    constexpr int   DL[3]  = {1, 3, 5};
    constexpr int   OL[3]  = {0, 1, 4};
    constexpr float C1A[3] = {0.57735026919f, 0.33333333333f, 0.25819888975f};
    const float INV_F  = 0.0078125f;           // 1/128 (q*k scaling)
    const float INV_SF = 0.08838834764831845f; // 1/sqrt(128)

    // ---- phase 0: stage T (bf16, transposed), S (bf16), w2 ----
    {
        const float4* Tg = (const float4*)(T + (size_t)n0 * 1152);
        // incremental (t9, dd) tracking: le = t9*9 + dd; start le = tid*4,
        // advance by 1024 elements per it (1024 = 113*9 + 7).
        int t9 = (tid * 4) / 9;
        int dd = tid * 4 - t9 * 9;
        #pragma unroll
        for (int it = 0; it < 18; ++it) {
            float4 val = Tg[it * 256 + tid];
            float vv[4] = {val.x, val.y, val.z, val.w};
            int t9c = t9, ddc = dd;
            #pragma unroll
            for (int e = 0; e < 4; ++e) {
                int n  = t9c >> 7;
                int uu = t9c & 127;
                sm.u.ttr[(n * 9 + ddc) * 136 + uu] = f2bf(vv[e]);
                ++ddc; if (ddc == 9) { ddc = 0; ++t9c; }
            }
            t9 += 113; dd += 7; if (dd >= 9) { dd -= 9; ++t9; }
        }
        const float4* Sg = (const float4*)(S + (size_t)n0 * 128);
        #pragma unroll
        for (int it = 0; it < 2; ++it) {
            int lin = (it * 256 + tid) * 4;
            float4 val = Sg[it * 256 + tid];
            int n = lin >> 7, uu = lin & 127;
            ushortx4 pk = { f2bf(val.x), f2bf(val.y), f2bf(val.z), f2bf(val.w) };
            *(ushortx4*)(&sm.sS[n * 136 + uu]) = pk;
        }
        for (int i = tid; i < 3 * FDIM; i += 256) sm.w2l[i] = w2[i];
    }
    __syncthreads();

    // ---- phase 2: q,k projections + in-lane s = sum_d C1 q k ----
    float sf[2][4] = {{0.f,0.f,0.f,0.f},{0.f,0.f,0.f,0.f}};
    #pragma unroll
    for (int l = 0; l < 3; ++l) {
        bf16x8 aq[2][4], ak[2][4];
        #pragma unroll
        for (int vt = 0; vt < 2; ++vt)
            #pragma unroll
            for (int kc = 0; kc < 4; ++kc) {
                int v  = w * 32 + vt * 16 + m16;
                int u0 = kc * 32 + quad * 8;
                aq[vt][kc] = *(const bf16x8*)(Wq + (l * 128 + v) * 128 + u0);
                ak[vt][kc] = *(const bf16x8*)(Wk + (l * 128 + v) * 128 + u0);
            }
        #pragma unroll
        for (int j = 0; j < DL[l]; ++j) {
            int jj = OL[l] + j;
            bf16x8 b[4];
            #pragma unroll
            for (int kc = 0; kc < 4; ++kc)
                b[kc] = *(const bf16x8*)(&sm.u.ttr[(m16 * 9 + jj) * 136 + kc * 32 + quad * 8]);
            floatx4 q0 = {0.f,0.f,0.f,0.f}, q1 = {0.f,0.f,0.f,0.f};
            floatx4 k0 = {0.f,0.f,0.f,0.f}, k1 = {0.f,0.f,0.f,0.f};
            #pragma unroll
            for (int kc = 0; kc < 4; ++kc) {
                q0 = mfma16(aq[0][kc], b[kc], q0);
                q1 = mfma16(aq[1][kc], b[kc], q1);
                k0 = mfma16(ak[0][kc], b[kc], k0);
                k1 = mfma16(ak[1][kc], b[kc], k1);
            }
            #pragma unroll
            for (int r = 0; r < 4; ++r) {
                sf[0][r] += C1A[l] * q0[r] * k0[r];
                sf[1][r] += C1A[l] * q1[r] * k1[r];
            }
        }
    }
    #pragma unroll
    for (int vt = 0; vt < 2; ++vt)
        #pragma unroll
        for (int r = 0; r < 4; ++r) {
            int uu = w * 32 + vt * 16 + quad * 4 + r;
            sm.sbuf[m16 * 136 + uu] = f2bf(sf[vt][r] * INV_F);
        }
    __syncthreads();

    // ---- phase 3: logits = ls_w @ s + ls_b ----
    // wave w owns row tiles {2w, 2w+1, 8+2w, 9+2w} so that lg[rt][r] is the
    // p value this very lane needs later (su: rt 0,1; sd: rt 2,3).
    float lg[4][4];
    {
        bf16x8 bs[4];
        #pragma unroll
        for (int kc = 0; kc < 4; ++kc)
            bs[kc] = *(const bf16x8*)(&sm.sbuf[m16 * 136 + kc * 32 + quad * 8]);
        #pragma unroll
        for (int rt = 0; rt < 4; ++rt) {
            int tile = (rt < 2) ? (2 * w + rt) : (6 + 2 * w + rt);  // 8+2w+(rt-2)
            floatx4 acc = {0.f,0.f,0.f,0.f};
            int ia = tile * 16 + m16;
            #pragma unroll
            for (int kc = 0; kc < 4; ++kc) {
                bf16x8 a = *(const bf16x8*)(Lsw + ia * 128 + kc * 32 + quad * 8);
                acc = mfma16(a, bs[kc], acc);
            }
            int i0 = tile * 16 + quad * 4;
            float4 bias = *(const float4*)(ls_b + i0);
            lg[rt][0] = acc[0] + bias.x;
            lg[rt][1] = acc[1] + bias.y;
            lg[rt][2] = acc[2] + bias.z;
            lg[rt][3] = acc[3] + bias.w;
        }
    }

    // ---- phase 4: softmax over 256 per node (col = m16); result stays in lg ----
    {
        float mx = lg[0][0];
        #pragma unroll
        for (int rt = 0; rt < 4; ++rt)
            #pragma unroll
            for (int r = 0; r < 4; ++r) mx = fmaxf(mx, lg[rt][r]);
        mx = fmaxf(mx, __shfl_xor(mx, 16, 64));
        mx = fmaxf(mx, __shfl_xor(mx, 32, 64));
        if (lane < 16) sm.redA[w * 16 + lane] = mx;
        __syncthreads();
        float m4 = fmaxf(fmaxf(sm.redA[m16], sm.redA[16 + m16]),
                         fmaxf(sm.redA[32 + m16], sm.redA[48 + m16]));
        float lsum = 0.f;
        #pragma unroll
        for (int rt = 0; rt < 4; ++rt)
            #pragma unroll
            for (int r = 0; r < 4; ++r) {
                float e = __expf(lg[rt][r] - m4);
                lg[rt][r] = e;
                lsum += e;
            }
        lsum += __shfl_xor(lsum, 16, 64);
        lsum += __shfl_xor(lsum, 32, 64);
        if (lane < 16) sm.redB[w * 16 + lane] = lsum;
        __syncthreads();
        float tot = sm.redB[m16] + sm.redB[16 + m16] + sm.redB[32 + m16] + sm.redB[48 + m16];
        float rinv = 1.0f / tot;
        #pragma unroll
        for (int rt = 0; rt < 4; ++rt)
            #pragma unroll
            for (int r = 0; r < 4; ++r)
                lg[rt][r] *= rinv;     // p values, kept in registers
    }
    // no barrier needed: phase 5 only reads LDS written before phase 2's barrier

    // ---- phase 5a: v projection (accumulate all 9 dims in regs) ----
    float sdv[2][4];
    #pragma unroll
    for (int vt = 0; vt < 2; ++vt)
        #pragma unroll
        for (int r = 0; r < 4; ++r)
            sdv[vt][r] = lg[2 + vt][r] * INV_SF;   // sd * 1/sqrt(F) folded

    floatx4 vacc[9][2];
    #pragma unroll
    for (int l = 0; l < 3; ++l) {
        bf16x8 av[2][4];
        #pragma unroll
        for (int vt = 0; vt < 2; ++vt)
            #pragma unroll
            for (int kc = 0; kc < 4; ++kc) {
                int v  = w * 32 + vt * 16 + m16;
                int u0 = kc * 32 + quad * 8;
                av[vt][kc] = *(const bf16x8*)(Wv + (l * 128 + v) * 128 + u0);
            }
        #pragma unroll
        for (int j = 0; j < DL[l]; ++j) {
            int jj = OL[l] + j;
            bf16x8 b[4];
            #pragma unroll
            for (int kc = 0; kc < 4; ++kc)
                b[kc] = *(const bf16x8*)(&sm.u.ttr[(m16 * 9 + jj) * 136 + kc * 32 + quad * 8]);
            floatx4 a0 = {0.f,0.f,0.f,0.f}, a1 = {0.f,0.f,0.f,0.f};
            #pragma unroll
            for (int kc = 0; kc < 4; ++kc) {
                a0 = mfma16(av[0][kc], b[kc], a0);
                a1 = mfma16(av[1][kc], b[kc], a1);
            }
            vacc[jj][0] = a0;
            vacc[jj][1] = a1;
        }
    }

    // ---- phase 6: out2 = su * silu(S @ lvs_w.T + lvs_b) ----
    // (hoisted before the staging barriers; touches only sS + lg + global)
    {
        bf16x8 bS[4];
        #pragma unroll
        for (int kc = 0; kc < 4; ++kc)
            bS[kc] = *(const bf16x8*)(&sm.sS[m16 * 136 + kc * 32 + quad * 8]);
        #pragma unroll
        for (int rt = 0; rt < 2; ++rt) {
            floatx4 acc = {0.f,0.f,0.f,0.f};
            int ia = (2 * w + rt) * 16 + m16;
            #pragma unroll
            for (int kc = 0; kc < 4; ++kc) {
                bf16x8 a = *(const bf16x8*)(Lvw + ia * 128 + kc * 32 + quad * 8);
                acc = mfma16(a, bS[kc], acc);
            }
            int i0 = (2 * w + rt) * 16 + quad * 4;
            float4 bias = *(const float4*)(lvs_b + i0);
            float bb[4] = {bias.x, bias.y, bias.z, bias.w};
            float o4[4];
            #pragma unroll
            for (int r = 0; r < 4; ++r) {
                float z   = acc[r] + bb[r];
                float sig = 1.0f / (1.0f + __expf(-z));
                float su  = lg[rt][r];          // su from registers (tile 2w+rt)
                o4[r] = su * z * sig;
            }
            *(float4*)(out + OUT2_OFF + (size_t)(n0 + m16) * 128 + i0) =
                make_float4(o4[0], o4[1], o4[2], o4[3]);
        }
    }

    __syncthreads();   // all waves done reading ttr; safe to reuse as tu staging

    // ---- phase 5b: tu staging (float4 LDS writes) + coalesced global store ----
    #pragma unroll
    for (int h = 0; h < 2; ++h) {
        if (((m16 >> 3) & 1) == h) {
            int n8 = m16 & 7;
            #pragma unroll
            for (int vt = 0; vt < 2; ++vt) {
                int u0 = w * 32 + vt * 16 + quad * 4;
                float vals[36];
                #pragma unroll
                for (int r = 0; r < 4; ++r) {
                    int uu = u0 + r;
                    float c0 = sdv[vt][r] * sm.w2l[uu];
                    float c1 = sdv[vt][r] * sm.w2l[128 + uu];
                    float c2 = sdv[vt][r] * sm.w2l[256 + uu];
                    vals[r * 9 + 0] = vacc[0][vt][r] * c0;
                    #pragma unroll
                    for (int j = 0; j < 3; ++j) vals[r * 9 + 1 + j] = vacc[1 + j][vt][r] * c1;
                    #pragma unroll
                    for (int j = 0; j < 5; ++j) vals[r * 9 + 4 + j] = vacc[4 + j][vt][r] * c2;
                }
                // 36 consecutive floats, 16-B aligned (u0*9 ≡ 0 mod 4, 1160 ≡ 0 mod 4)
                float4* dst = (float4*)(&sm.u.tu8[n8 * 1160 + u0 * 9]);
                #pragma unroll
                for (int q4 = 0; q4 < 9; ++q4)
                    dst[q4] = make_float4(vals[q4 * 4 + 0], vals[q4 * 4 + 1],
                                          vals[q4 * 4 + 2], vals[q4 * 4 + 3]);
            }
        }
        __syncthreads();
        float* outt = out + (size_t)(n0 + h * 8) * 1152;
        #pragma unroll
        for (int it = 0; it < 9; ++it) {
            int lin = it * 1024 + tid * 4;
            int n8  = lin / 1152;
            int r   = lin - n8 * 1152;
            float4 v4 = *(const float4*)(&sm.u.tu8[n8 * 1160 + r]);
            *(float4*)(outt + (size_t)n8 * 1152 + r) = v4;
        }
        if (h == 0) __syncthreads();
    }
}

extern "C" void kernel_launch(void* const* d_in, const int* in_sizes, int n_in,
                              void* d_out, int out_size, void* d_ws, size_t ws_size,
                              hipStream_t stream) {
    const float* T   = (const float*)d_in[0];
    const float* S   = (const float*)d_in[1];
    const float* Wq  = (const float*)d_in[2];
    const float* Wk  = (const float*)d_in[3];
    const float* Wv  = (const float*)d_in[4];
    const float* w2  = (const float*)d_in[5];
    const float* lsw = (const float*)d_in[6];
    const float* lsb = (const float*)d_in[7];
    const float* lvw = (const float*)d_in[8];
    const float* lvb = (const float*)d_in[9];
    float* out = (float*)d_out;
    unsigned short* wbf = (unsigned short*)d_ws;

    if (ws_size < WS_ELEMS * sizeof(unsigned short)) return;  // workspace guard (needs 384 KB)

    prep_kernel<<<(WS_ELEMS + 255) / 256, 256, 0, stream>>>(Wq, Wk, Wv, lsw, lvw, wbf);
    tpattn_main<<<NBLK, 256, 0, stream>>>(T, S, w2, lsb, lvb, wbf, out);
}

// Round 3
// 571.203 us; speedup vs baseline: 1.0419x; 1.0019x over previous
//
#include <hip/hip_runtime.h>

// Problem constants
#define N_NODES 49152
#define FDIM    128
#define DDIM    9
#define NB      16                       // nodes per block
#define NBLK    (N_NODES / NB)           // 3072
#define OUT2_OFF ((size_t)N_NODES * FDIM * DDIM)

// ws layout (ushort elements): Wq[3][128][128], Wk, Wv, ls_w[256][128], lvs_w[128][128]
#define WQ_OFF   0
#define WK_OFF   49152
#define WV_OFF   98304
#define LS_OFF   147456
#define LVS_OFF  180224
#define WS_ELEMS 196608

typedef __bf16 bf16x8 __attribute__((ext_vector_type(8)));
typedef float  floatx4 __attribute__((ext_vector_type(4)));
typedef unsigned short ushortx4 __attribute__((ext_vector_type(4)));

__device__ __forceinline__ unsigned short f2bf(float f) {
    unsigned u = __float_as_uint(f);
    u += 0x7FFFu + ((u >> 16) & 1u);      // RNE; inputs are finite Gaussians
    return (unsigned short)(u >> 16);
}

__device__ __forceinline__ floatx4 mfma16(bf16x8 a, bf16x8 b, floatx4 c) {
    return __builtin_amdgcn_mfma_f32_16x16x32_bf16(a, b, c, 0, 0, 0);
}

// ---------------- prep: cast all weights to bf16 into ws ----------------
__global__ void prep_kernel(const float* __restrict__ Wq, const float* __restrict__ Wk,
                            const float* __restrict__ Wv, const float* __restrict__ lsw,
                            const float* __restrict__ lvw, unsigned short* __restrict__ ws) {
    int i = blockIdx.x * 256 + threadIdx.x;
    if (i >= WS_ELEMS) return;
    float v;
    if      (i < WK_OFF)  v = Wq[i - WQ_OFF];
    else if (i < WV_OFF)  v = Wk[i - WK_OFF];
    else if (i < LS_OFF)  v = Wv[i - WV_OFF];
    else if (i < LVS_OFF) v = lsw[i - LS_OFF];
    else                  v = lvw[i - LVS_OFF];
    ws[i] = f2bf(v);
}

// ---------------- fused main kernel ----------------
// LDS 49920 B -> 3 blocks/CU. p (softmax probs) lives in registers via the
// logit tile remap (wave w owns tiles {2w, 2w+1, 8+2w, 9+2w}); tu goes out
// through LDS staging (union with ttr) so every HBM line is written fully.
// Occupancy is pinned with amdgpu_waves_per_eu(3,3): a min-only bound
// (launch_bounds(256,3)) let the allocator chase 6 waves/EU at 84 VGPRs,
// spilling ~50 floats/thread to scratch (+150 MB deterministic HBM writes).
// With (3,3) the register budget is 168 and the whole phase-5/6 state
// (vacc 72 + sdv/su/vals) stays in registers.
struct SMem {
    union {
        unsigned short ttr[NB * DDIM * 136];  // T transposed [n][dd][u], bf16 (39168 B)
        float tu8[8 * 1160];                  // tu staging, 8 nodes, pad 1160 (37120 B)
    } u;
    unsigned short sS[NB * 136];              // S bf16 [n][u]
    unsigned short sbuf[NB * 136];            // s bf16 [n][u]
    float w2l[3 * FDIM];                      // w2 fp32
    float redA[64];
    float redB[64];
};

__global__ void __launch_bounds__(256) __attribute__((amdgpu_waves_per_eu(3, 3)))
tpattn_main(const float* __restrict__ T, const float* __restrict__ S,
            const float* __restrict__ w2, const float* __restrict__ ls_b,
            const float* __restrict__ lvs_b, const unsigned short* __restrict__ wbf,
            float* __restrict__ out) {
    __shared__ SMem sm;
    const int tid  = threadIdx.x;
    const int w    = tid >> 6;       // wave 0..3
    const int lane = tid & 63;
    const int quad = lane >> 4;
    const int m16  = lane & 15;      // node col for B/D; row for A loads
    const int n0   = blockIdx.x * NB;

    const unsigned short* Wq  = wbf + WQ_OFF;
    const unsigned short* Wk  = wbf + WK_OFF;
    const unsigned short* Wv  = wbf + WV_OFF;
    const unsigned short* Lsw = wbf + LS_OFF;
    const unsigned short* Lvw = wbf + LVS_OFF;

    constexpr int   DL[3]  = {1, 3, 5};
    constexpr int   OL[3]  = {0, 1, 4};
    constexpr float C1A[3] = {0.57735026919f, 0.33333333333f, 0.25819888975f};
    const float INV_F  = 0.0078125f;           // 1/128 (q*k scaling)
    const float INV_SF = 0.08838834764831845f; // 1/sqrt(128)

    // ---- phase 0: stage T (bf16, transposed), S (bf16), w2 ----
    {
        const float4* Tg = (const float4*)(T + (size_t)n0 * 1152);
        // incremental (t9, dd) tracking: le = t9*9 + dd; start le = tid*4,
        // advance by 1024 elements per it (1024 = 113*9 + 7).
        int t9 = (tid * 4) / 9;
        int dd = tid * 4 - t9 * 9;
        #pragma unroll
        for (int it = 0; it < 18; ++it) {
            float4 val = Tg[it * 256 + tid];
            float vv[4] = {val.x, val.y, val.z, val.w};
            int t9c = t9, ddc = dd;
            #pragma unroll
            for (int e = 0; e < 4; ++e) {
                int n  = t9c >> 7;
                int uu = t9c & 127;
                sm.u.ttr[(n * 9 + ddc) * 136 + uu] = f2bf(vv[e]);
                ++ddc; if (ddc == 9) { ddc = 0; ++t9c; }
            }
            t9 += 113; dd += 7; if (dd >= 9) { dd -= 9; ++t9; }
        }
        const float4* Sg = (const float4*)(S + (size_t)n0 * 128);
        #pragma unroll
        for (int it = 0; it < 2; ++it) {
            int lin = (it * 256 + tid) * 4;
            float4 val = Sg[it * 256 + tid];
            int n = lin >> 7, uu = lin & 127;
            ushortx4 pk = { f2bf(val.x), f2bf(val.y), f2bf(val.z), f2bf(val.w) };
            *(ushortx4*)(&sm.sS[n * 136 + uu]) = pk;
        }
        for (int i = tid; i < 3 * FDIM; i += 256) sm.w2l[i] = w2[i];
    }
    __syncthreads();

    // ---- phase 2: q,k projections + in-lane s = sum_d C1 q k ----
    float sf[2][4] = {{0.f,0.f,0.f,0.f},{0.f,0.f,0.f,0.f}};
    #pragma unroll
    for (int l = 0; l < 3; ++l) {
        bf16x8 aq[2][4], ak[2][4];
        #pragma unroll
        for (int vt = 0; vt < 2; ++vt)
            #pragma unroll
            for (int kc = 0; kc < 4; ++kc) {
                int v  = w * 32 + vt * 16 + m16;
                int u0 = kc * 32 + quad * 8;
                aq[vt][kc] = *(const bf16x8*)(Wq + (l * 128 + v) * 128 + u0);
                ak[vt][kc] = *(const bf16x8*)(Wk + (l * 128 + v) * 128 + u0);
            }
        #pragma unroll
        for (int j = 0; j < DL[l]; ++j) {
            int jj = OL[l] + j;
            bf16x8 b[4];
            #pragma unroll
            for (int kc = 0; kc < 4; ++kc)
                b[kc] = *(const bf16x8*)(&sm.u.ttr[(m16 * 9 + jj) * 136 + kc * 32 + quad * 8]);
            floatx4 q0 = {0.f,0.f,0.f,0.f}, q1 = {0.f,0.f,0.f,0.f};
            floatx4 k0 = {0.f,0.f,0.f,0.f}, k1 = {0.f,0.f,0.f,0.f};
            #pragma unroll
            for (int kc = 0; kc < 4; ++kc) {
                q0 = mfma16(aq[0][kc], b[kc], q0);
                q1 = mfma16(aq[1][kc], b[kc], q1);
                k0 = mfma16(ak[0][kc], b[kc], k0);
                k1 = mfma16(ak[1][kc], b[kc], k1);
            }
            #pragma unroll
            for (int r = 0; r < 4; ++r) {
                sf[0][r] += C1A[l] * q0[r] * k0[r];
                sf[1][r] += C1A[l] * q1[r] * k1[r];
            }
        }
    }
    #pragma unroll
    for (int vt = 0; vt < 2; ++vt)
        #pragma unroll
        for (int r = 0; r < 4; ++r) {
            int uu = w * 32 + vt * 16 + quad * 4 + r;
            sm.sbuf[m16 * 136 + uu] = f2bf(sf[vt][r] * INV_F);
        }
    __syncthreads();

    // ---- phase 3: logits = ls_w @ s + ls_b ----
    // wave w owns row tiles {2w, 2w+1, 8+2w, 9+2w} so that lg[rt][r] is the
    // p value this very lane needs later (su: rt 0,1; sd: rt 2,3).
    float lg[4][4];
    {
        bf16x8 bs[4];
        #pragma unroll
        for (int kc = 0; kc < 4; ++kc)
            bs[kc] = *(const bf16x8*)(&sm.sbuf[m16 * 136 + kc * 32 + quad * 8]);
        #pragma unroll
        for (int rt = 0; rt < 4; ++rt) {
            int tile = (rt < 2) ? (2 * w + rt) : (6 + 2 * w + rt);  // 8+2w+(rt-2)
            floatx4 acc = {0.f,0.f,0.f,0.f};
            int ia = tile * 16 + m16;
            #pragma unroll
            for (int kc = 0; kc < 4; ++kc) {
                bf16x8 a = *(const bf16x8*)(Lsw + ia * 128 + kc * 32 + quad * 8);
                acc = mfma16(a, bs[kc], acc);
            }
            int i0 = tile * 16 + quad * 4;
            float4 bias = *(const float4*)(ls_b + i0);
            lg[rt][0] = acc[0] + bias.x;
            lg[rt][1] = acc[1] + bias.y;
            lg[rt][2] = acc[2] + bias.z;
            lg[rt][3] = acc[3] + bias.w;
        }
    }

    // ---- phase 4: softmax over 256 per node (col = m16); result stays in lg ----
    {
        float mx = lg[0][0];
        #pragma unroll
        for (int rt = 0; rt < 4; ++rt)
            #pragma unroll
            for (int r = 0; r < 4; ++r) mx = fmaxf(mx, lg[rt][r]);
        mx = fmaxf(mx, __shfl_xor(mx, 16, 64));
        mx = fmaxf(mx, __shfl_xor(mx, 32, 64));
        if (lane < 16) sm.redA[w * 16 + lane] = mx;
        __syncthreads();
        float m4 = fmaxf(fmaxf(sm.redA[m16], sm.redA[16 + m16]),
                         fmaxf(sm.redA[32 + m16], sm.redA[48 + m16]));
        float lsum = 0.f;
        #pragma unroll
        for (int rt = 0; rt < 4; ++rt)
            #pragma unroll
            for (int r = 0; r < 4; ++r) {
                float e = __expf(lg[rt][r] - m4);
                lg[rt][r] = e;
                lsum += e;
            }
        lsum += __shfl_xor(lsum, 16, 64);
        lsum += __shfl_xor(lsum, 32, 64);
        if (lane < 16) sm.redB[w * 16 + lane] = lsum;
        __syncthreads();
        float tot = sm.redB[m16] + sm.redB[16 + m16] + sm.redB[32 + m16] + sm.redB[48 + m16];
        float rinv = 1.0f / tot;
        #pragma unroll
        for (int rt = 0; rt < 4; ++rt)
            #pragma unroll
            for (int r = 0; r < 4; ++r)
                lg[rt][r] *= rinv;     // p values, kept in registers
    }
    // no barrier needed: phase 5 only reads LDS written before phase 2's barrier

    // ---- phase 5a: v projection (accumulate all 9 dims in regs) ----
    float sdv[2][4];
    #pragma unroll
    for (int vt = 0; vt < 2; ++vt)
        #pragma unroll
        for (int r = 0; r < 4; ++r)
            sdv[vt][r] = lg[2 + vt][r] * INV_SF;   // sd * 1/sqrt(F) folded

    floatx4 vacc[9][2];
    #pragma unroll
    for (int l = 0; l < 3; ++l) {
        bf16x8 av[2][4];
        #pragma unroll
        for (int vt = 0; vt < 2; ++vt)
            #pragma unroll
            for (int kc = 0; kc < 4; ++kc) {
                int v  = w * 32 + vt * 16 + m16;
                int u0 = kc * 32 + quad * 8;
                av[vt][kc] = *(const bf16x8*)(Wv + (l * 128 + v) * 128 + u0);
            }
        #pragma unroll
        for (int j = 0; j < DL[l]; ++j) {
            int jj = OL[l] + j;
            bf16x8 b[4];
            #pragma unroll
            for (int kc = 0; kc < 4; ++kc)
                b[kc] = *(const bf16x8*)(&sm.u.ttr[(m16 * 9 + jj) * 136 + kc * 32 + quad * 8]);
            floatx4 a0 = {0.f,0.f,0.f,0.f}, a1 = {0.f,0.f,0.f,0.f};
            #pragma unroll
            for (int kc = 0; kc < 4; ++kc) {
                a0 = mfma16(av[0][kc], b[kc], a0);
                a1 = mfma16(av[1][kc], b[kc], a1);
            }
            vacc[jj][0] = a0;
            vacc[jj][1] = a1;
        }
    }

    // ---- phase 6: out2 = su * silu(S @ lvs_w.T + lvs_b) ----
    // (hoisted before the staging barriers; touches only sS + lg + global)
    {
        bf16x8 bS[4];
        #pragma unroll
        for (int kc = 0; kc < 4; ++kc)
            bS[kc] = *(const bf16x8*)(&sm.sS[m16 * 136 + kc * 32 + quad * 8]);
        #pragma unroll
        for (int rt = 0; rt < 2; ++rt) {
            floatx4 acc = {0.f,0.f,0.f,0.f};
            int ia = (2 * w + rt) * 16 + m16;
            #pragma unroll
            for (int kc = 0; kc < 4; ++kc) {
                bf16x8 a = *(const bf16x8*)(Lvw + ia * 128 + kc * 32 + quad * 8);
                acc = mfma16(a, bS[kc], acc);
            }
            int i0 = (2 * w + rt) * 16 + quad * 4;
            float4 bias = *(const float4*)(lvs_b + i0);
            float bb[4] = {bias.x, bias.y, bias.z, bias.w};
            float o4[4];
            #pragma unroll
            for (int r = 0; r < 4; ++r) {
                float z   = acc[r] + bb[r];
                float sig = 1.0f / (1.0f + __expf(-z));
                float su  = lg[rt][r];          // su from registers (tile 2w+rt)
                o4[r] = su * z * sig;
            }
            *(float4*)(out + OUT2_OFF + (size_t)(n0 + m16) * 128 + i0) =
                make_float4(o4[0], o4[1], o4[2], o4[3]);
        }
    }

    __syncthreads();   // all waves done reading ttr; safe to reuse as tu staging

    // ---- phase 5b: tu staging (float4 LDS writes) + coalesced global store ----
    #pragma unroll
    for (int h = 0; h < 2; ++h) {
        if (((m16 >> 3) & 1) == h) {
            int n8 = m16 & 7;
            #pragma unroll
            for (int vt = 0; vt < 2; ++vt) {
                int u0 = w * 32 + vt * 16 + quad * 4;
                float vals[36];
                #pragma unroll
                for (int r = 0; r < 4; ++r) {
                    int uu = u0 + r;
                    float c0 = sdv[vt][r] * sm.w2l[uu];
                    float c1 = sdv[vt][r] * sm.w2l[128 + uu];
                    float c2 = sdv[vt][r] * sm.w2l[256 + uu];
                    vals[r * 9 + 0] = vacc[0][vt][r] * c0;
                    #pragma unroll
                    for (int j = 0; j < 3; ++j) vals[r * 9 + 1 + j] = vacc[1 + j][vt][r] * c1;
                    #pragma unroll
                    for (int j = 0; j < 5; ++j) vals[r * 9 + 4 + j] = vacc[4 + j][vt][r] * c2;
                }
                // 36 consecutive floats, 16-B aligned (u0*9 ≡ 0 mod 4, 1160 ≡ 0 mod 4)
                float4* dst = (float4*)(&sm.u.tu8[n8 * 1160 + u0 * 9]);
                #pragma unroll
                for (int q4 = 0; q4 < 9; ++q4)
                    dst[q4] = make_float4(vals[q4 * 4 + 0], vals[q4 * 4 + 1],
                                          vals[q4 * 4 + 2], vals[q4 * 4 + 3]);
            }
        }
        __syncthreads();
        float* outt = out + (size_t)(n0 + h * 8) * 1152;
        #pragma unroll
        for (int it = 0; it < 9; ++it) {
            int lin = it * 1024 + tid * 4;
            int n8  = lin / 1152;
            int r   = lin - n8 * 1152;
            float4 v4 = *(const float4*)(&sm.u.tu8[n8 * 1160 + r]);
            *(float4*)(outt + (size_t)n8 * 1152 + r) = v4;
        }
        if (h == 0) __syncthreads();
    }
}

extern "C" void kernel_launch(void* const* d_in, const int* in_sizes, int n_in,
                              void* d_out, int out_size, void* d_ws, size_t ws_size,
                              hipStream_t stream) {
    const float* T   = (const float*)d_in[0];
    const float* S   = (const float*)d_in[1];
    const float* Wq  = (const float*)d_in[2];
    const float* Wk  = (const float*)d_in[3];
    const float* Wv  = (const float*)d_in[4];
    const float* w2  = (const float*)d_in[5];
    const float* lsw = (const float*)d_in[6];
    const float* lsb = (const float*)d_in[7];
    const float* lvw = (const float*)d_in[8];
    const float* lvb = (const float*)d_in[9];
    float* out = (float*)d_out;
    unsigned short* wbf = (unsigned short*)d_ws;

    if (ws_size < WS_ELEMS * sizeof(unsigned short)) return;  // workspace guard (needs 384 KB)

    prep_kernel<<<(WS_ELEMS + 255) / 256, 256, 0, stream>>>(Wq, Wk, Wv, lsw, lvw, wbf);
    tpattn_main<<<NBLK, 256, 0, stream>>>(T, S, w2, lsb, lvb, wbf, out);
}

// Round 4
// 551.056 us; speedup vs baseline: 1.0799x; 1.0366x over previous
//
#include <hip/hip_runtime.h>

// Problem constants
#define N_NODES 49152
#define FDIM    128
#define DDIM    9
#define NB      16                       // nodes per block
#define NBLK    (N_NODES / NB)           // 3072
#define OUT2_OFF ((size_t)N_NODES * FDIM * DDIM)

// ws layout (ushort elements): Wq[3][128][128], Wk, Wv, ls_w[256][128], lvs_w[128][128]
#define WQ_OFF   0
#define WK_OFF   49152
#define WV_OFF   98304
#define LS_OFF   147456
#define LVS_OFF  180224
#define WS_ELEMS 196608

typedef __bf16 bf16x8 __attribute__((ext_vector_type(8)));
typedef float  floatx4 __attribute__((ext_vector_type(4)));
typedef unsigned short ushortx4 __attribute__((ext_vector_type(4)));

__device__ __forceinline__ unsigned short f2bf(float f) {
    unsigned u = __float_as_uint(f);
    u += 0x7FFFu + ((u >> 16) & 1u);      // RNE; inputs are finite Gaussians
    return (unsigned short)(u >> 16);
}

__device__ __forceinline__ floatx4 mfma16(bf16x8 a, bf16x8 b, floatx4 c) {
    return __builtin_amdgcn_mfma_f32_16x16x32_bf16(a, b, c, 0, 0, 0);
}

// ---------------- prep: cast all weights to bf16 into ws ----------------
__global__ void prep_kernel(const float* __restrict__ Wq, const float* __restrict__ Wk,
                            const float* __restrict__ Wv, const float* __restrict__ lsw,
                            const float* __restrict__ lvw, unsigned short* __restrict__ ws) {
    int i = blockIdx.x * 256 + threadIdx.x;
    if (i >= WS_ELEMS) return;
    float v;
    if      (i < WK_OFF)  v = Wq[i - WQ_OFF];
    else if (i < WV_OFF)  v = Wk[i - WK_OFF];
    else if (i < LS_OFF)  v = Wv[i - WV_OFF];
    else if (i < LVS_OFF) v = lsw[i - LS_OFF];
    else                  v = lvw[i - LVS_OFF];
    ws[i] = f2bf(v);
}

// ---------------- fused main kernel ----------------
// LDS 49920 B -> 3 blocks/CU possible. p (softmax probs) lives in registers
// via the logit tile remap (wave w owns tiles {2w, 2w+1, 8+2w, 9+2w}); tu
// goes out through LDS staging (union with ttr) so HBM lines are written
// whole.
// Register discipline (rounds 1-3 post-mortem): requesting min 3 waves/EU
// (launch_bounds(256,3) or waves_per_eu(3,3)) made the backend clamp to 84
// arch-VGPRs and spill ~50 floats/thread => +150 MiB deterministic HBM
// writes (+200 B/thread) and +70 MiB fetch per dispatch. launch_bounds(256,2)
// (cap 256) is the empirically spill-free config. Phase 6 (out2) runs AFTER
// the tu staging so its bS[4]+acc regs sit outside the peak-pressure window
// (vacc 72 + vals 36 + sdv/su 16) keeping peak ~140 < 168 (3 waves/SIMD).
struct SMem {
    union {
        unsigned short ttr[NB * DDIM * 136];  // T transposed [n][dd][u], bf16 (39168 B)
        float tu8[8 * 1160];                  // tu staging, 8 nodes, pad 1160 (37120 B)
    } u;
    unsigned short sS[NB * 136];              // S bf16 [n][u]
    unsigned short sbuf[NB * 136];            // s bf16 [n][u]
    float w2l[3 * FDIM];                      // w2 fp32
    float redA[64];
    float redB[64];
};

__global__ void __launch_bounds__(256, 2)
tpattn_main(const float* __restrict__ T, const float* __restrict__ S,
            const float* __restrict__ w2, const float* __restrict__ ls_b,
            const float* __restrict__ lvs_b, const unsigned short* __restrict__ wbf,
            float* __restrict__ out) {
    __shared__ SMem sm;
    const int tid  = threadIdx.x;
    const int w    = tid >> 6;       // wave 0..3
    const int lane = tid & 63;
    const int quad = lane >> 4;
    const int m16  = lane & 15;      // node col for B/D; row for A loads
    const int n0   = blockIdx.x * NB;

    const unsigned short* Wq  = wbf + WQ_OFF;
    const unsigned short* Wk  = wbf + WK_OFF;
    const unsigned short* Wv  = wbf + WV_OFF;
    const unsigned short* Lsw = wbf + LS_OFF;
    const unsigned short* Lvw = wbf + LVS_OFF;

    constexpr int   DL[3]  = {1, 3, 5};
    constexpr int   OL[3]  = {0, 1, 4};
    constexpr float C1A[3] = {0.57735026919f, 0.33333333333f, 0.25819888975f};
    const float INV_F  = 0.0078125f;           // 1/128 (q*k scaling)
    const float INV_SF = 0.08838834764831845f; // 1/sqrt(128)

    // ---- phase 0: stage T (bf16, transposed), S (bf16), w2 ----
    {
        const float4* Tg = (const float4*)(T + (size_t)n0 * 1152);
        // incremental (t9, dd) tracking: le = t9*9 + dd; start le = tid*4,
        // advance by 1024 elements per it (1024 = 113*9 + 7).
        int t9 = (tid * 4) / 9;
        int dd = tid * 4 - t9 * 9;
        #pragma unroll
        for (int it = 0; it < 18; ++it) {
            float4 val = Tg[it * 256 + tid];
            float vv[4] = {val.x, val.y, val.z, val.w};
            int t9c = t9, ddc = dd;
            #pragma unroll
            for (int e = 0; e < 4; ++e) {
                int n  = t9c >> 7;
                int uu = t9c & 127;
                sm.u.ttr[(n * 9 + ddc) * 136 + uu] = f2bf(vv[e]);
                ++ddc; if (ddc == 9) { ddc = 0; ++t9c; }
            }
            t9 += 113; dd += 7; if (dd >= 9) { dd -= 9; ++t9; }
        }
        const float4* Sg = (const float4*)(S + (size_t)n0 * 128);
        #pragma unroll
        for (int it = 0; it < 2; ++it) {
            int lin = (it * 256 + tid) * 4;
            float4 val = Sg[it * 256 + tid];
            int n = lin >> 7, uu = lin & 127;
            ushortx4 pk = { f2bf(val.x), f2bf(val.y), f2bf(val.z), f2bf(val.w) };
            *(ushortx4*)(&sm.sS[n * 136 + uu]) = pk;
        }
        for (int i = tid; i < 3 * FDIM; i += 256) sm.w2l[i] = w2[i];
    }
    __syncthreads();

    // ---- phase 2: q,k projections + in-lane s = sum_d C1 q k ----
    float sf[2][4] = {{0.f,0.f,0.f,0.f},{0.f,0.f,0.f,0.f}};
    #pragma unroll
    for (int l = 0; l < 3; ++l) {
        bf16x8 aq[2][4], ak[2][4];
        #pragma unroll
        for (int vt = 0; vt < 2; ++vt)
            #pragma unroll
            for (int kc = 0; kc < 4; ++kc) {
                int v  = w * 32 + vt * 16 + m16;
                int u0 = kc * 32 + quad * 8;
                aq[vt][kc] = *(const bf16x8*)(Wq + (l * 128 + v) * 128 + u0);
                ak[vt][kc] = *(const bf16x8*)(Wk + (l * 128 + v) * 128 + u0);
            }
        #pragma unroll
        for (int j = 0; j < DL[l]; ++j) {
            int jj = OL[l] + j;
            bf16x8 b[4];
            #pragma unroll
            for (int kc = 0; kc < 4; ++kc)
                b[kc] = *(const bf16x8*)(&sm.u.ttr[(m16 * 9 + jj) * 136 + kc * 32 + quad * 8]);
            floatx4 q0 = {0.f,0.f,0.f,0.f}, q1 = {0.f,0.f,0.f,0.f};
            floatx4 k0 = {0.f,0.f,0.f,0.f}, k1 = {0.f,0.f,0.f,0.f};
            #pragma unroll
            for (int kc = 0; kc < 4; ++kc) {
                q0 = mfma16(aq[0][kc], b[kc], q0);
                q1 = mfma16(aq[1][kc], b[kc], q1);
                k0 = mfma16(ak[0][kc], b[kc], k0);
                k1 = mfma16(ak[1][kc], b[kc], k1);
            }
            #pragma unroll
            for (int r = 0; r < 4; ++r) {
                sf[0][r] += C1A[l] * q0[r] * k0[r];
                sf[1][r] += C1A[l] * q1[r] * k1[r];
            }
        }
    }
    #pragma unroll
    for (int vt = 0; vt < 2; ++vt)
        #pragma unroll
        for (int r = 0; r < 4; ++r) {
            int uu = w * 32 + vt * 16 + quad * 4 + r;
            sm.sbuf[m16 * 136 + uu] = f2bf(sf[vt][r] * INV_F);
        }
    __syncthreads();

    // ---- phase 3: logits = ls_w @ s + ls_b ----
    // wave w owns row tiles {2w, 2w+1, 8+2w, 9+2w} so that lg[rt][r] is the
    // p value this very lane needs later (su: rt 0,1; sd: rt 2,3).
    float lg[4][4];
    {
        bf16x8 bs[4];
        #pragma unroll
        for (int kc = 0; kc < 4; ++kc)
            bs[kc] = *(const bf16x8*)(&sm.sbuf[m16 * 136 + kc * 32 + quad * 8]);
        #pragma unroll
        for (int rt = 0; rt < 4; ++rt) {
            int tile = (rt < 2) ? (2 * w + rt) : (6 + 2 * w + rt);  // 8+2w+(rt-2)
            floatx4 acc = {0.f,0.f,0.f,0.f};
            int ia = tile * 16 + m16;
            #pragma unroll
            for (int kc = 0; kc < 4; ++kc) {
                bf16x8 a = *(const bf16x8*)(Lsw + ia * 128 + kc * 32 + quad * 8);
                acc = mfma16(a, bs[kc], acc);
            }
            int i0 = tile * 16 + quad * 4;
            float4 bias = *(const float4*)(ls_b + i0);
            lg[rt][0] = acc[0] + bias.x;
            lg[rt][1] = acc[1] + bias.y;
            lg[rt][2] = acc[2] + bias.z;
            lg[rt][3] = acc[3] + bias.w;
        }
    }

    // ---- phase 4: softmax over 256 per node (col = m16); result stays in lg ----
    {
        float mx = lg[0][0];
        #pragma unroll
        for (int rt = 0; rt < 4; ++rt)
            #pragma unroll
            for (int r = 0; r < 4; ++r) mx = fmaxf(mx, lg[rt][r]);
        mx = fmaxf(mx, __shfl_xor(mx, 16, 64));
        mx = fmaxf(mx, __shfl_xor(mx, 32, 64));
        if (lane < 16) sm.redA[w * 16 + lane] = mx;
        __syncthreads();
        float m4 = fmaxf(fmaxf(sm.redA[m16], sm.redA[16 + m16]),
                         fmaxf(sm.redA[32 + m16], sm.redA[48 + m16]));
        float lsum = 0.f;
        #pragma unroll
        for (int rt = 0; rt < 4; ++rt)
            #pragma unroll
            for (int r = 0; r < 4; ++r) {
                float e = __expf(lg[rt][r] - m4);
                lg[rt][r] = e;
                lsum += e;
            }
        lsum += __shfl_xor(lsum, 16, 64);
        lsum += __shfl_xor(lsum, 32, 64);
        if (lane < 16) sm.redB[w * 16 + lane] = lsum;
        __syncthreads();
        float tot = sm.redB[m16] + sm.redB[16 + m16] + sm.redB[32 + m16] + sm.redB[48 + m16];
        float rinv = 1.0f / tot;
        #pragma unroll
        for (int rt = 0; rt < 4; ++rt)
            #pragma unroll
            for (int r = 0; r < 4; ++r)
                lg[rt][r] *= rinv;     // p values, kept in registers
    }
    // no barrier needed: phase 5 only reads LDS written before phase 2's barrier

    // ---- phase 5a: v projection (accumulate all 9 dims in regs) ----
    float sdv[2][4];
    #pragma unroll
    for (int vt = 0; vt < 2; ++vt)
        #pragma unroll
        for (int r = 0; r < 4; ++r)
            sdv[vt][r] = lg[2 + vt][r] * INV_SF;   // sd * 1/sqrt(F) folded

    floatx4 vacc[9][2];
    #pragma unroll
    for (int l = 0; l < 3; ++l) {
        bf16x8 av[2][4];
        #pragma unroll
        for (int vt = 0; vt < 2; ++vt)
            #pragma unroll
            for (int kc = 0; kc < 4; ++kc) {
                int v  = w * 32 + vt * 16 + m16;
                int u0 = kc * 32 + quad * 8;
                av[vt][kc] = *(const bf16x8*)(Wv + (l * 128 + v) * 128 + u0);
            }
        #pragma unroll
        for (int j = 0; j < DL[l]; ++j) {
            int jj = OL[l] + j;
            bf16x8 b[4];
            #pragma unroll
            for (int kc = 0; kc < 4; ++kc)
                b[kc] = *(const bf16x8*)(&sm.u.ttr[(m16 * 9 + jj) * 136 + kc * 32 + quad * 8]);
            floatx4 a0 = {0.f,0.f,0.f,0.f}, a1 = {0.f,0.f,0.f,0.f};
            #pragma unroll
            for (int kc = 0; kc < 4; ++kc) {
                a0 = mfma16(av[0][kc], b[kc], a0);
                a1 = mfma16(av[1][kc], b[kc], a1);
            }
            vacc[jj][0] = a0;
            vacc[jj][1] = a1;
        }
    }

    __syncthreads();   // all waves done reading ttr; safe to reuse as tu staging

    // ---- phase 5b: tu staging (float4 LDS writes) + coalesced global store ----
    #pragma unroll
    for (int h = 0; h < 2; ++h) {
        if (((m16 >> 3) & 1) == h) {
            int n8 = m16 & 7;
            #pragma unroll
            for (int vt = 0; vt < 2; ++vt) {
                int u0 = w * 32 + vt * 16 + quad * 4;
                float vals[36];
                #pragma unroll
                for (int r = 0; r < 4; ++r) {
                    int uu = u0 + r;
                    float c0 = sdv[vt][r] * sm.w2l[uu];
                    float c1 = sdv[vt][r] * sm.w2l[128 + uu];
                    float c2 = sdv[vt][r] * sm.w2l[256 + uu];
                    vals[r * 9 + 0] = vacc[0][vt][r] * c0;
                    #pragma unroll
                    for (int j = 0; j < 3; ++j) vals[r * 9 + 1 + j] = vacc[1 + j][vt][r] * c1;
                    #pragma unroll
                    for (int j = 0; j < 5; ++j) vals[r * 9 + 4 + j] = vacc[4 + j][vt][r] * c2;
                }
                // 36 consecutive floats, 16-B aligned (u0*9 ≡ 0 mod 4, 1160 ≡ 0 mod 4)
                float4* dst = (float4*)(&sm.u.tu8[n8 * 1160 + u0 * 9]);
                #pragma unroll
                for (int q4 = 0; q4 < 9; ++q4)
                    dst[q4] = make_float4(vals[q4 * 4 + 0], vals[q4 * 4 + 1],
                                          vals[q4 * 4 + 2], vals[q4 * 4 + 3]);
            }
        }
        __syncthreads();
        float* outt = out + (size_t)(n0 + h * 8) * 1152;
        #pragma unroll
        for (int it = 0; it < 9; ++it) {
            int lin = it * 1024 + tid * 4;
            int n8  = lin / 1152;
            int r   = lin - n8 * 1152;
            float4 v4 = *(const float4*)(&sm.u.tu8[n8 * 1160 + r]);
            *(float4*)(outt + (size_t)n8 * 1152 + r) = v4;
        }
        if (h == 0) __syncthreads();
    }

    // ---- phase 6: out2 = su * silu(S @ lvs_w.T + lvs_b) ----
    // (after staging: keeps bS/acc out of the peak-register window; reads
    // only sS (non-union LDS) + lg su values, so no extra barrier needed)
    {
        bf16x8 bS[4];
        #pragma unroll
        for (int kc = 0; kc < 4; ++kc)
            bS[kc] = *(const bf16x8*)(&sm.sS[m16 * 136 + kc * 32 + quad * 8]);
        #pragma unroll
        for (int rt = 0; rt < 2; ++rt) {
            floatx4 acc = {0.f,0.f,0.f,0.f};
            int ia = (2 * w + rt) * 16 + m16;
            #pragma unroll
            for (int kc = 0; kc < 4; ++kc) {
                bf16x8 a = *(const bf16x8*)(Lvw + ia * 128 + kc * 32 + quad * 8);
                acc = mfma16(a, bS[kc], acc);
            }
            int i0 = (2 * w + rt) * 16 + quad * 4;
            float4 bias = *(const float4*)(lvs_b + i0);
            float bb[4] = {bias.x, bias.y, bias.z, bias.w};
            float o4[4];
            #pragma unroll
            for (int r = 0; r < 4; ++r) {
                float z   = acc[r] + bb[r];
                float sig = 1.0f / (1.0f + __expf(-z));
                float su  = lg[rt][r];          // su from registers (tile 2w+rt)
                o4[r] = su * z * sig;
            }
            *(float4*)(out + OUT2_OFF + (size_t)(n0 + m16) * 128 + i0) =
                make_float4(o4[0], o4[1], o4[2], o4[3]);
        }
    }
}

extern "C" void kernel_launch(void* const* d_in, const int* in_sizes, int n_in,
                              void* d_out, int out_size, void* d_ws, size_t ws_size,
                              hipStream_t stream) {
    const float* T   = (const float*)d_in[0];
    const float* S   = (const float*)d_in[1];
    const float* Wq  = (const float*)d_in[2];
    const float* Wk  = (const float*)d_in[3];
    const float* Wv  = (const float*)d_in[4];
    const float* w2  = (const float*)d_in[5];
    const float* lsw = (const float*)d_in[6];
    const float* lsb = (const float*)d_in[7];
    const float* lvw = (const float*)d_in[8];
    const float* lvb = (const float*)d_in[9];
    float* out = (float*)d_out;
    unsigned short* wbf = (unsigned short*)d_ws;

    if (ws_size < WS_ELEMS * sizeof(unsigned short)) return;  // workspace guard (needs 384 KB)

    prep_kernel<<<(WS_ELEMS + 255) / 256, 256, 0, stream>>>(Wq, Wk, Wv, lsw, lvw, wbf);
    tpattn_main<<<NBLK, 256, 0, stream>>>(T, S, w2, lsb, lvb, wbf, out);
}